// Round 4
// baseline (499.451 us; speedup 1.0000x reference)
//
#include <hip/hip_runtime.h>
#include <math.h>

#define NCD 16
#define NTD 24
#define NPIX 65536

struct c32 { float x, y; };

__device__ __forceinline__ c32 cadd(c32 a, c32 b){ return {a.x+b.x, a.y+b.y}; }
__device__ __forceinline__ c32 csub(c32 a, c32 b){ return {a.x-b.x, a.y-b.y}; }
__device__ __forceinline__ c32 cmul(c32 a, c32 b){ return {a.x*b.x - a.y*b.y, a.x*b.y + a.y*b.x}; }
__device__ __forceinline__ c32 cnegi(c32 a){ return {a.y, -a.x}; }   // -i*a

__device__ __forceinline__ unsigned short f2h(float f) {
  return __builtin_bit_cast(unsigned short, (_Float16)f);
}
__device__ __forceinline__ float h2f(unsigned short s) {
  return (float)__builtin_bit_cast(_Float16, s);
}
__device__ __forceinline__ unsigned int pk2(c32 v) {
  return (unsigned int)f2h(v.x) | ((unsigned int)f2h(v.y) << 16);
}
__device__ __forceinline__ c32 up2(unsigned int u) {
  c32 r; r.x = h2f((unsigned short)(u & 0xffffu)); r.y = h2f((unsigned short)(u >> 16));
  return r;
}

__constant__ float W16R_[16] = {
  1.0f, 0.9238795325f, 0.7071067812f, 0.3826834324f,
  0.0f,-0.3826834324f,-0.7071067812f,-0.9238795325f,
 -1.0f,-0.9238795325f,-0.7071067812f,-0.3826834324f,
  0.0f, 0.3826834324f, 0.7071067812f, 0.9238795325f };
__constant__ float W16I_[16] = {
  0.0f,-0.3826834324f,-0.7071067812f,-0.9238795325f,
 -1.0f,-0.9238795325f,-0.7071067812f,-0.3826834324f,
  0.0f, 0.3826834324f, 0.7071067812f, 0.9238795325f,
  1.0f, 0.9238795325f, 0.7071067812f, 0.3826834324f };

__device__ __forceinline__ int revmap(int p) { return ((p & 3) << 2) | (p >> 2); }

// 16-pt DFT in registers. Output X[k] at v[revmap(k)].
__device__ __forceinline__ void dft16(c32 v[16]) {
  c32 y[16];
#pragma unroll
  for (int j = 0; j < 4; ++j) {
    c32 a = v[j], b = v[j+4], c = v[j+8], d = v[j+12];
    c32 t0 = cadd(a,c), t1 = csub(a,c), t2 = cadd(b,d), t3 = cnegi(csub(b,d));
    y[j] = cadd(t0,t2);
    if (j == 0) {
      y[4]  = cadd(t1,t3);
      y[8]  = csub(t0,t2);
      y[12] = csub(t1,t3);
    } else {
      c32 w1 = {W16R_[j],        W16I_[j]};
      c32 w2 = {W16R_[(2*j)&15], W16I_[(2*j)&15]};
      c32 w3 = {W16R_[(3*j)&15], W16I_[(3*j)&15]};
      y[4+j]  = cmul(cadd(t1,t3), w1);
      y[8+j]  = cmul(csub(t0,t2), w2);
      y[12+j] = cmul(csub(t1,t3), w3);
    }
  }
#pragma unroll
  for (int q = 0; q < 4; ++q) {
    c32 a = y[4*q], b = y[4*q+1], c = y[4*q+2], d = y[4*q+3];
    c32 t0 = cadd(a,c), t1 = csub(a,c), t2 = cadd(b,d), t3 = cnegi(csub(b,d));
    v[4*q+0] = cadd(t0,t2);
    v[4*q+1] = cadd(t1,t3);
    v[4*q+2] = csub(t0,t2);
    v[4*q+3] = csub(t1,t3);
  }
}

// 256-pt FFT, fp32 mid-exchange (c32 lds[0..4096)). Twiddles packed half2.
__device__ __forceinline__ void fft256(c32 v[16], const unsigned int twh[16],
                                       c32* lds, int g, int lane) {
  dft16(v);
#pragma unroll
  for (int p = 0; p < 16; ++p) v[p] = cmul(v[p], up2(twh[p]));
  __syncthreads();
#pragma unroll
  for (int p = 0; p < 16; ++p) {
    int k1 = revmap(p);
    lds[g*256 + k1*16 + (lane ^ k1)] = v[p];
  }
  __syncthreads();
#pragma unroll
  for (int j = 0; j < 16; ++j)
    v[j] = lds[g*256 + lane*16 + (j ^ lane)];
  dft16(v);
}

// 256-pt FFT, fp16-packed mid-exchange (uint ldsu[0..4352), stride-17 pad).
__device__ __forceinline__ void fft256h(c32 v[16], const unsigned int twh[16],
                                        unsigned int* ldsu, int g, int lane) {
  dft16(v);
#pragma unroll
  for (int p = 0; p < 16; ++p) v[p] = cmul(v[p], up2(twh[p]));
  __syncthreads();
#pragma unroll
  for (int p = 0; p < 16; ++p) {
    int k1 = revmap(p);
    ldsu[g*272 + k1*17 + lane] = pk2(v[p]);   // pad 17: 2-way banks (free)
  }
  __syncthreads();
#pragma unroll
  for (int j = 0; j < 16; ++j)
    v[j] = up2(ldsu[g*272 + lane*17 + j]);
  dft16(v);
}

// --- kS: smaps [nx][ny][c] (split re/im) -> smapsTh[c][nx][ny] packed half2 ---
__global__ __launch_bounds__(256) void kS(const float* __restrict__ sre,
                                          const float* __restrict__ sim,
                                          unsigned int* __restrict__ smapsTh) {
  __shared__ float lre[16*260];
  __shared__ float lim[16*260];
  int nx = blockIdx.x, tid = threadIdx.x;
#pragma unroll
  for (int it = 0; it < 16; ++it) {
    int e = it*256 + tid;          // e = ny*16 + c
    int ny = e >> 4, c = e & 15;
    lre[c*260 + ny] = sre[(size_t)nx*4096 + e];
    lim[c*260 + ny] = sim[(size_t)nx*4096 + e];
  }
  __syncthreads();
#pragma unroll
  for (int c = 0; c < 16; ++c) {
    c32 v = { lre[c*260 + tid], lim[c*260 + tid] };
    smapsTh[(size_t)c*NPIX + nx*256 + tid] = pk2(v);
  }
}

// --- kW: bilinear warp + (-1)^{nx+ny} sign -> wh[t][nx][ny] packed half2 ---
__global__ __launch_bounds__(256) void kW(const float* __restrict__ ire,
                                          const float* __restrict__ iim,
                                          const float* __restrict__ flow,
                                          unsigned int* __restrict__ wh) {
  __shared__ float fl[256*49];
  int nx = blockIdx.x, tid = threadIdx.x;
  const float* src = flow + (size_t)nx*12288;     // [ny][d][t] slice
#pragma unroll
  for (int it = 0; it < 48; ++it) {
    int e = it*256 + tid;
    fl[(e/48)*49 + (e%48)] = src[e];
  }
  __syncthreads();
  int ny = tid;
  float s = ((nx + ny) & 1) ? -1.0f : 1.0f;
  for (int t = 0; t < NTD; ++t) {
    float fx = fl[ny*49 + t];
    float fy = fl[ny*49 + 24 + t];
    float xf = fminf(fmaxf((float)nx + fx, 0.0f), 255.0f);
    float yf = fminf(fmaxf((float)ny + fy, 0.0f), 255.0f);
    float x0f = fminf(floorf(xf), 254.0f);
    float y0f = fminf(floorf(yf), 254.0f);
    int i00 = (int)x0f * 256 + (int)y0f;
    float wx = xf - x0f, wy = yf - y0f;
    float w00 = (1.f-wx)*(1.f-wy), w01 = (1.f-wx)*wy;
    float w10 = wx*(1.f-wy),       w11 = wx*wy;
    float re = w00*ire[i00] + w01*ire[i00+1] + w10*ire[i00+256] + w11*ire[i00+257];
    float im = w00*iim[i00] + w01*iim[i00+1] + w10*iim[i00+256] + w11*iim[i00+257];
    c32 v = { re*s, im*s };
    wh[(size_t)t*NPIX + nx*256 + ny] = pk2(v);
  }
}

// --- kM: mask [kx][ky][c][t] -> fp16 maskTh[lt][ky][c][pos], pos=nibbleswap(kx)
__global__ __launch_bounds__(256) void kM(const float* __restrict__ mask,
                                          unsigned int* __restrict__ maskTh,
                                          int t0, int chunkT) {
  __shared__ unsigned short lm[256*49];
  int ky = blockIdx.x, c0 = blockIdx.y*2, tid = threadIdx.x;
  int nct = 2*chunkT;              // <= 48
  int total = 256*nct;
  for (int e = tid; e < total; e += 256) {
    int kx = e / nct, ctl = e - kx*nct;
    int hi = (ctl >= chunkT) ? 1 : 0;
    int cc = c0 + hi;
    int tt = t0 + ctl - hi*chunkT;
    lm[kx*49 + ctl] = f2h(mask[(size_t)kx*98304 + ky*384 + cc*24 + tt]);
  }
  __syncthreads();
  int wtotal = nct*128;
  for (int e = tid; e < wtotal; e += 256) {
    int ctl = e >> 7;
    int posh = (e & 127) * 2;      // even pos; write pair (posh, posh+1) as uint
    int hi = (ctl >= chunkT) ? 1 : 0;
    int cc = c0 + hi;
    int ltt = ctl - hi*chunkT;
    int kxa = ((posh & 15) << 4) | (posh >> 4);
    int kxb = (((posh+1) & 15) << 4) | ((posh+1) >> 4);
    unsigned int a = lm[kxa*49 + ctl], b = lm[kxb*49 + ctl];
    size_t base = (((((size_t)ltt*256 + ky)*16 + cc) << 8) + posh) >> 1;
    maskTh[base] = a | (b << 16);
  }
}

// --- kA: row FFTs along ny -> Y1h[lt][c][ky][nx] packed half2 ---
__global__ __launch_bounds__(256, 4) void kA(const unsigned int* __restrict__ wh,
                                             const unsigned int* __restrict__ smapsTh,
                                             unsigned int* __restrict__ Y1h, int t0) {
  __shared__ unsigned int fftws[4352];   // 17 KB fp16 fft mid-exchange
  __shared__ unsigned int stage[4096];   // 16 KB output staging (disjoint!)
  int tid = threadIdx.x, g = tid >> 4, lane = tid & 15;
  int lt = blockIdx.y, t = t0 + lt;
  int nx0 = blockIdx.x*16, nx = nx0 + g;
  int c0 = blockIdx.z*4;

  unsigned int wr[16];
  const unsigned int* wrow = wh + (size_t)t*NPIX + nx*256;
#pragma unroll
  for (int n1 = 0; n1 < 16; ++n1) wr[n1] = wrow[n1*16 + lane];

  unsigned int twh[16];
#pragma unroll
  for (int p = 0; p < 16; ++p) {
    int k1 = revmap(p);
    float ang = -6.283185307179586f * (float)(lane * k1) * (1.0f/256.0f);
    float sv, cv; __sincosf(ang, &sv, &cv);
    c32 tw; tw.x = cv; tw.y = sv;
    twh[p] = pk2(tw);
  }

  // prefetch coil 0 smaps row
  unsigned int su[16];
  {
    const unsigned int* srow = smapsTh + (size_t)c0*NPIX + nx*256;
#pragma unroll
    for (int n1 = 0; n1 < 16; ++n1) su[n1] = srow[n1*16 + lane];
  }

  for (int ci = 0; ci < 4; ++ci) {
    int c = c0 + ci;
    c32 v[16];
#pragma unroll
    for (int n1 = 0; n1 < 16; ++n1) v[n1] = cmul(up2(wr[n1]), up2(su[n1]));
    if (ci < 3) {                  // prefetch next coil (hidden under fft)
      const unsigned int* srow = smapsTh + (size_t)(c + 1)*NPIX + nx*256;
#pragma unroll
      for (int n1 = 0; n1 < 16; ++n1) su[n1] = srow[n1*16 + lane];
    }
    fft256h(v, twh, fftws, g, lane);
    // stage disjoint from fftws: safe without extra barrier
#pragma unroll
    for (int p = 0; p < 16; ++p) {
      int ky = lane + 16*revmap(p);    // ky & 15 == lane
      stage[ky*16 + (g ^ lane)] = pk2(v[p]);
    }
    __syncthreads();
    unsigned int* dst = Y1h + (((size_t)lt*16 + c) << 16) + nx0;
#pragma unroll
    for (int it = 0; it < 16; ++it) {
      int e = it*256 + tid;
      int ky = e >> 4, j = e & 15;
      dst[(size_t)ky*256 + j] = stage[ky*16 + (j ^ (ky & 15))];
    }
    // next fft256h's first barrier protects stage reads vs next writes
  }
}

// --- kB: column FFTs + mask-weighted t-reduction -> out, no atomics ---
__global__ __launch_bounds__(256, 4) void kB(const unsigned int* __restrict__ Y1h,
                                             const unsigned int* __restrict__ maskTh,
                                             float* __restrict__ out,
                                             int chunkT, int accum) {
  __shared__ c32 lds[4096];        // 32 KB (fft mid fp32 + final reduction)
  int tid = threadIdx.x, g = tid >> 4, lane = tid & 15;
  int ci = g & 3, tp = g >> 2;     // 4 coils x 4 t-phases
  int cq = blockIdx.x, ky = blockIdx.y;
  int c = cq*4 + ci;

  unsigned int twh[16];
#pragma unroll
  for (int p = 0; p < 16; ++p) {
    int k1 = revmap(p);
    float ang = -6.283185307179586f * (float)(lane * k1) * (1.0f/256.0f);
    float sv, cv; __sincosf(ang, &sv, &cv);
    c32 tw; tw.x = cv; tw.y = sv;
    twh[p] = pk2(tw);
  }

  c32 acc[16];
#pragma unroll
  for (int p = 0; p < 16; ++p) { acc[p].x = 0.f; acc[p].y = 0.f; }
  float wsc = (((lane + ky) & 1) ? -1.0f : 1.0f) * (1.0f/256.0f);

  int iters = (chunkT + 3) >> 2;
  unsigned int u[16];
#pragma unroll
  for (int n1 = 0; n1 < 16; ++n1) u[n1] = 0;
  if (tp < chunkT) {
    const unsigned int* row = Y1h + ((size_t)(tp*16 + c)*256 + ky)*256;
#pragma unroll
    for (int n1 = 0; n1 < 16; ++n1) u[n1] = row[n1*16 + lane];
  }

  for (int ii = 0; ii < iters; ++ii) {
    int lt = tp + 4*ii;
    bool act = lt < chunkT;
    int lts = act ? lt : 0;
    // mask loads issued first; consumed only after the fft
    const unsigned int* mp = maskTh
        + (((((size_t)lts*256 + ky)*16 + c) << 8) >> 1) + lane*8;
    unsigned int mu[8];
#pragma unroll
    for (int q = 0; q < 8; ++q) mu[q] = mp[q];
    c32 v[16];
#pragma unroll
    for (int n1 = 0; n1 < 16; ++n1) v[n1] = up2(u[n1]);
    int ltn = tp + 4*(ii+1);
    if (ltn < chunkT) {            // prefetch next Y1 row
      const unsigned int* row = Y1h + ((size_t)(ltn*16 + c)*256 + ky)*256;
#pragma unroll
      for (int n1 = 0; n1 < 16; ++n1) u[n1] = row[n1*16 + lane];
    }
    fft256(v, twh, lds, g, lane);
    if (act) {
#pragma unroll
      for (int p = 0; p < 16; ++p) {
        int j = revmap(p);         // pos = lane*16 + j holds kx = lane + 16*j
        unsigned int um = mu[j >> 1];
        unsigned short us = (j & 1) ? (unsigned short)(um >> 16)
                                    : (unsigned short)(um & 0xffffu);
        float m = h2f(us) * wsc;
        acc[p].x += v[p].x * m;
        acc[p].y += v[p].y * m;
      }
    }
  }
  __syncthreads();
#pragma unroll
  for (int p = 0; p < 16; ++p) lds[g*256 + p*16 + lane] = acc[p];
  __syncthreads();
  // thread tid = kx; gather 4 tp partials x 4 coils, write float4 per plane
  int kx = tid;
  int lane2 = kx & 15, pp = revmap(kx >> 4);
  float vre[4], vim[4];
#pragma unroll
  for (int c2 = 0; c2 < 4; ++c2) {
    float sx = 0.f, sy = 0.f;
#pragma unroll
    for (int t2 = 0; t2 < 4; ++t2) {
      c32 a = lds[(t2*4 + c2)*256 + pp*16 + lane2];
      sx += a.x; sy += a.y;
    }
    vre[c2] = sx; vim[c2] = sy;
  }
  size_t o = (((size_t)kx << 8) + ky)*16 + cq*4;
  float4* pre = (float4*)(out + o);
  float4* pim = (float4*)(out + (size_t)NPIX*NCD + o);
  float4 R = {vre[0], vre[1], vre[2], vre[3]};
  float4 I = {vim[0], vim[1], vim[2], vim[3]};
  if (accum) {
    float4 r0 = *pre, i0 = *pim;
    R.x += r0.x; R.y += r0.y; R.z += r0.z; R.w += r0.w;
    I.x += i0.x; I.y += i0.y; I.z += i0.z; I.w += i0.w;
  }
  *pre = R; *pim = I;
}

extern "C" void kernel_launch(void* const* d_in, const int* in_sizes, int n_in,
                              void* d_out, int out_size, void* d_ws, size_t ws_size,
                              hipStream_t stream) {
  const float* ire  = (const float*)d_in[0];
  const float* iim  = (const float*)d_in[1];
  const float* mask = (const float*)d_in[2];
  const float* sre  = (const float*)d_in[3];
  const float* sim  = (const float*)d_in[4];
  const float* flow = (const float*)d_in[5];
  float* out = (float*)d_out;

  char* ws = (char*)d_ws;
  const size_t smapsT_b = (size_t)NCD * NPIX * 4;             // 4 MB packed
  const size_t w_b      = (size_t)NTD * NPIX * 4;             // 6.3 MB packed
  unsigned int* smapsTh = (unsigned int*)ws;
  unsigned int* whbuf   = (unsigned int*)(ws + smapsT_b);
  size_t base = smapsT_b + w_b;
  size_t rem  = (ws_size > base) ? ws_size - base : 0;

  const size_t maskT_per_t = (size_t)NPIX * NCD * 2;          // 2 MB (fp16)
  const size_t y1_per_t    = (size_t)NCD * NPIX * 4;          // 4 MB (half2)
  int chunk = 1;
  const int cands[8] = {24, 12, 8, 6, 4, 3, 2, 1};
  for (int i = 0; i < 8; ++i) {
    if ((size_t)cands[i] * (maskT_per_t + y1_per_t) <= rem) { chunk = cands[i]; break; }
  }
  unsigned int* maskTh = (unsigned int*)(ws + base);
  unsigned int* Y1h    = (unsigned int*)(ws + base + (size_t)chunk * maskT_per_t);

  kS<<<256, 256, 0, stream>>>(sre, sim, smapsTh);
  kW<<<256, 256, 0, stream>>>(ire, iim, flow, whbuf);
  for (int t0 = 0; t0 < NTD; t0 += chunk) {
    kM<<<dim3(256, 8), 256, 0, stream>>>(mask, maskTh, t0, chunk);
    kA<<<dim3(16, chunk, 4), 256, 0, stream>>>(whbuf, smapsTh, Y1h, t0);
    kB<<<dim3(4, 256), 256, 0, stream>>>(Y1h, maskTh, out, chunk, t0 > 0 ? 1 : 0);
  }
}

// Round 5
// 286.534 us; speedup vs baseline: 1.7431x; 1.7431x over previous
//
#include <hip/hip_runtime.h>
#include <math.h>

#define NCD 16
#define NTD 24
#define NPIX 65536

struct c32 { float x, y; };

__device__ __forceinline__ c32 cadd(c32 a, c32 b){ return {a.x+b.x, a.y+b.y}; }
__device__ __forceinline__ c32 csub(c32 a, c32 b){ return {a.x-b.x, a.y-b.y}; }
__device__ __forceinline__ c32 cmul(c32 a, c32 b){ return {a.x*b.x - a.y*b.y, a.x*b.y + a.y*b.x}; }
__device__ __forceinline__ c32 cnegi(c32 a){ return {a.y, -a.x}; }   // -i*a

__device__ __forceinline__ unsigned short f2h(float f) {
  return __builtin_bit_cast(unsigned short, (_Float16)f);
}
__device__ __forceinline__ float h2f(unsigned short s) {
  return (float)__builtin_bit_cast(_Float16, s);
}
__device__ __forceinline__ unsigned int pk2(c32 v) {
  return (unsigned int)f2h(v.x) | ((unsigned int)f2h(v.y) << 16);
}
__device__ __forceinline__ c32 up2(unsigned int u) {
  c32 r; r.x = h2f((unsigned short)(u & 0xffffu)); r.y = h2f((unsigned short)(u >> 16));
  return r;
}

__constant__ float W16R_[16] = {
  1.0f, 0.9238795325f, 0.7071067812f, 0.3826834324f,
  0.0f,-0.3826834324f,-0.7071067812f,-0.9238795325f,
 -1.0f,-0.9238795325f,-0.7071067812f,-0.3826834324f,
  0.0f, 0.3826834324f, 0.7071067812f, 0.9238795325f };
__constant__ float W16I_[16] = {
  0.0f,-0.3826834324f,-0.7071067812f,-0.9238795325f,
 -1.0f,-0.9238795325f,-0.7071067812f,-0.3826834324f,
  0.0f, 0.3826834324f, 0.7071067812f, 0.9238795325f,
  1.0f, 0.9238795325f, 0.7071067812f, 0.3826834324f };

__device__ __forceinline__ int revmap(int p) { return ((p & 3) << 2) | (p >> 2); }

// 16-pt DFT in registers. Output X[k] at v[revmap(k)].
__device__ __forceinline__ void dft16(c32 v[16]) {
  c32 y[16];
#pragma unroll
  for (int j = 0; j < 4; ++j) {
    c32 a = v[j], b = v[j+4], c = v[j+8], d = v[j+12];
    c32 t0 = cadd(a,c), t1 = csub(a,c), t2 = cadd(b,d), t3 = cnegi(csub(b,d));
    y[j] = cadd(t0,t2);
    if (j == 0) {
      y[4]  = cadd(t1,t3);
      y[8]  = csub(t0,t2);
      y[12] = csub(t1,t3);
    } else {
      c32 w1 = {W16R_[j],        W16I_[j]};
      c32 w2 = {W16R_[(2*j)&15], W16I_[(2*j)&15]};
      c32 w3 = {W16R_[(3*j)&15], W16I_[(3*j)&15]};
      y[4+j]  = cmul(cadd(t1,t3), w1);
      y[8+j]  = cmul(csub(t0,t2), w2);
      y[12+j] = cmul(csub(t1,t3), w3);
    }
  }
#pragma unroll
  for (int q = 0; q < 4; ++q) {
    c32 a = y[4*q], b = y[4*q+1], c = y[4*q+2], d = y[4*q+3];
    c32 t0 = cadd(a,c), t1 = csub(a,c), t2 = cadd(b,d), t3 = cnegi(csub(b,d));
    v[4*q+0] = cadd(t0,t2);
    v[4*q+1] = cadd(t1,t3);
    v[4*q+2] = csub(t0,t2);
    v[4*q+3] = csub(t1,t3);
  }
}

// 256-pt FFT, fp32 mid-exchange (c32 lds[0..4096)). Twiddles packed half2.
__device__ __forceinline__ void fft256(c32 v[16], const unsigned int twh[16],
                                       c32* lds, int g, int lane) {
  dft16(v);
#pragma unroll
  for (int p = 0; p < 16; ++p) v[p] = cmul(v[p], up2(twh[p]));
  __syncthreads();
#pragma unroll
  for (int p = 0; p < 16; ++p) {
    int k1 = revmap(p);
    lds[g*256 + k1*16 + (lane ^ k1)] = v[p];
  }
  __syncthreads();
#pragma unroll
  for (int j = 0; j < 16; ++j)
    v[j] = lds[g*256 + lane*16 + (j ^ lane)];
  dft16(v);
}

// 256-pt FFT, fp16-packed mid-exchange (uint ldsu[0..4352), stride-17 pad).
__device__ __forceinline__ void fft256h(c32 v[16], const unsigned int twh[16],
                                        unsigned int* ldsu, int g, int lane) {
  dft16(v);
#pragma unroll
  for (int p = 0; p < 16; ++p) v[p] = cmul(v[p], up2(twh[p]));
  __syncthreads();
#pragma unroll
  for (int p = 0; p < 16; ++p) {
    int k1 = revmap(p);
    ldsu[g*272 + k1*17 + lane] = pk2(v[p]);   // pad 17: 2-way banks (free)
  }
  __syncthreads();
#pragma unroll
  for (int j = 0; j < 16; ++j)
    v[j] = up2(ldsu[g*272 + lane*17 + j]);
  dft16(v);
}

// --- kS: smaps [nx][ny][c] (split re/im) -> smapsTh[c][nx][ny] packed half2 ---
__global__ __launch_bounds__(256) void kS(const float* __restrict__ sre,
                                          const float* __restrict__ sim,
                                          unsigned int* __restrict__ smapsTh) {
  __shared__ float lre[16*260];
  __shared__ float lim[16*260];
  int nx = blockIdx.x, tid = threadIdx.x;
#pragma unroll
  for (int it = 0; it < 16; ++it) {
    int e = it*256 + tid;          // e = ny*16 + c
    int ny = e >> 4, c = e & 15;
    lre[c*260 + ny] = sre[(size_t)nx*4096 + e];
    lim[c*260 + ny] = sim[(size_t)nx*4096 + e];
  }
  __syncthreads();
#pragma unroll
  for (int c = 0; c < 16; ++c) {
    c32 v = { lre[c*260 + tid], lim[c*260 + tid] };
    smapsTh[(size_t)c*NPIX + nx*256 + tid] = pk2(v);
  }
}

// --- kW: bilinear warp + (-1)^{nx+ny} sign -> wh[t][nx][ny] packed half2 ---
__global__ __launch_bounds__(256) void kW(const float* __restrict__ ire,
                                          const float* __restrict__ iim,
                                          const float* __restrict__ flow,
                                          unsigned int* __restrict__ wh) {
  __shared__ float fl[256*49];
  int nx = blockIdx.x, tid = threadIdx.x;
  const float* src = flow + (size_t)nx*12288;     // [ny][d][t] slice
#pragma unroll
  for (int it = 0; it < 48; ++it) {
    int e = it*256 + tid;
    fl[(e/48)*49 + (e%48)] = src[e];
  }
  __syncthreads();
  int ny = tid;
  float s = ((nx + ny) & 1) ? -1.0f : 1.0f;
  for (int t = 0; t < NTD; ++t) {
    float fx = fl[ny*49 + t];
    float fy = fl[ny*49 + 24 + t];
    float xf = fminf(fmaxf((float)nx + fx, 0.0f), 255.0f);
    float yf = fminf(fmaxf((float)ny + fy, 0.0f), 255.0f);
    float x0f = fminf(floorf(xf), 254.0f);
    float y0f = fminf(floorf(yf), 254.0f);
    int i00 = (int)x0f * 256 + (int)y0f;
    float wx = xf - x0f, wy = yf - y0f;
    float w00 = (1.f-wx)*(1.f-wy), w01 = (1.f-wx)*wy;
    float w10 = wx*(1.f-wy),       w11 = wx*wy;
    float re = w00*ire[i00] + w01*ire[i00+1] + w10*ire[i00+256] + w11*ire[i00+257];
    float im = w00*iim[i00] + w01*iim[i00+1] + w10*iim[i00+256] + w11*iim[i00+257];
    c32 v = { re*s, im*s };
    wh[(size_t)t*NPIX + nx*256 + ny] = pk2(v);
  }
}

// --- kM: mask [kx][ky][c][t] -> fp16 maskTh[lt][ky][c][pos], pos=nibbleswap(kx)
__global__ __launch_bounds__(256) void kM(const float* __restrict__ mask,
                                          unsigned int* __restrict__ maskTh,
                                          int t0, int chunkT) {
  __shared__ unsigned short lm[256*49];
  int ky = blockIdx.x, c0 = blockIdx.y*2, tid = threadIdx.x;
  int nct = 2*chunkT;              // <= 48
  int total = 256*nct;
  for (int e = tid; e < total; e += 256) {
    int kx = e / nct, ctl = e - kx*nct;
    int hi = (ctl >= chunkT) ? 1 : 0;
    int cc = c0 + hi;
    int tt = t0 + ctl - hi*chunkT;
    lm[kx*49 + ctl] = f2h(mask[(size_t)kx*98304 + ky*384 + cc*24 + tt]);
  }
  __syncthreads();
  int wtotal = nct*128;
  for (int e = tid; e < wtotal; e += 256) {
    int ctl = e >> 7;
    int posh = (e & 127) * 2;      // even pos; write pair (posh, posh+1) as uint
    int hi = (ctl >= chunkT) ? 1 : 0;
    int cc = c0 + hi;
    int ltt = ctl - hi*chunkT;
    int kxa = ((posh & 15) << 4) | (posh >> 4);
    int kxb = (((posh+1) & 15) << 4) | ((posh+1) >> 4);
    unsigned int a = lm[kxa*49 + ctl], b = lm[kxb*49 + ctl];
    size_t base = (((((size_t)ltt*256 + ky)*16 + cc) << 8) + posh) >> 1;
    maskTh[base] = a | (b << 16);
  }
}

// --- kA: row FFTs along ny -> Y1h[lt][c][ky][nx] packed half2 ---
__global__ __launch_bounds__(256) void kA(const unsigned int* __restrict__ wh,
                                          const unsigned int* __restrict__ smapsTh,
                                          unsigned int* __restrict__ Y1h, int t0) {
  __shared__ unsigned int fftws[4352];   // 17 KB fp16 fft mid-exchange
  __shared__ unsigned int stage[4096];   // 16 KB output staging (disjoint!)
  int tid = threadIdx.x, g = tid >> 4, lane = tid & 15;
  int lt = blockIdx.y, t = t0 + lt;
  int nx0 = blockIdx.x*16, nx = nx0 + g;
  int c0 = blockIdx.z*4;

  unsigned int wr[16];
  const unsigned int* wrow = wh + (size_t)t*NPIX + nx*256;
#pragma unroll
  for (int n1 = 0; n1 < 16; ++n1) wr[n1] = wrow[n1*16 + lane];

  unsigned int twh[16];
#pragma unroll
  for (int p = 0; p < 16; ++p) {
    int k1 = revmap(p);
    float ang = -6.283185307179586f * (float)(lane * k1) * (1.0f/256.0f);
    float sv, cv; __sincosf(ang, &sv, &cv);
    c32 tw; tw.x = cv; tw.y = sv;
    twh[p] = pk2(tw);
  }

  // prefetch coil 0 smaps row
  unsigned int su[16];
  {
    const unsigned int* srow = smapsTh + (size_t)c0*NPIX + nx*256;
#pragma unroll
    for (int n1 = 0; n1 < 16; ++n1) su[n1] = srow[n1*16 + lane];
  }

  for (int ci = 0; ci < 4; ++ci) {
    int c = c0 + ci;
    c32 v[16];
#pragma unroll
    for (int n1 = 0; n1 < 16; ++n1) v[n1] = cmul(up2(wr[n1]), up2(su[n1]));
    if (ci < 3) {                  // prefetch next coil (hidden under fft)
      const unsigned int* srow = smapsTh + (size_t)(c + 1)*NPIX + nx*256;
#pragma unroll
      for (int n1 = 0; n1 < 16; ++n1) su[n1] = srow[n1*16 + lane];
    }
    fft256h(v, twh, fftws, g, lane);
    // stage disjoint from fftws: safe without extra barrier
#pragma unroll
    for (int p = 0; p < 16; ++p) {
      int ky = lane + 16*revmap(p);    // ky & 15 == lane
      stage[ky*16 + (g ^ lane)] = pk2(v[p]);
    }
    __syncthreads();
    unsigned int* dst = Y1h + (((size_t)lt*16 + c) << 16) + nx0;
#pragma unroll
    for (int it = 0; it < 16; ++it) {
      int e = it*256 + tid;
      int ky = e >> 4, j = e & 15;
      dst[(size_t)ky*256 + j] = stage[ky*16 + (j ^ (ky & 15))];
    }
    // next fft256h's first barrier protects stage reads vs next writes
  }
}

// --- kB: column FFTs + mask-weighted t-reduction -> out, no atomics ---
__global__ __launch_bounds__(256) void kB(const unsigned int* __restrict__ Y1h,
                                          const unsigned int* __restrict__ maskTh,
                                          float* __restrict__ out,
                                          int chunkT, int accum) {
  __shared__ c32 lds[4096];        // 32 KB (fft mid fp32 + final reduction)
  int tid = threadIdx.x, g = tid >> 4, lane = tid & 15;
  int ci = g & 3, tp = g >> 2;     // 4 coils x 4 t-phases
  int cq = blockIdx.x, ky = blockIdx.y;
  int c = cq*4 + ci;

  unsigned int twh[16];
#pragma unroll
  for (int p = 0; p < 16; ++p) {
    int k1 = revmap(p);
    float ang = -6.283185307179586f * (float)(lane * k1) * (1.0f/256.0f);
    float sv, cv; __sincosf(ang, &sv, &cv);
    c32 tw; tw.x = cv; tw.y = sv;
    twh[p] = pk2(tw);
  }

  c32 acc[16];
#pragma unroll
  for (int p = 0; p < 16; ++p) { acc[p].x = 0.f; acc[p].y = 0.f; }
  float wsc = (((lane + ky) & 1) ? -1.0f : 1.0f) * (1.0f/256.0f);

  int iters = (chunkT + 3) >> 2;
  unsigned int u[16];
#pragma unroll
  for (int n1 = 0; n1 < 16; ++n1) u[n1] = 0;
  if (tp < chunkT) {
    const unsigned int* row = Y1h + ((size_t)(tp*16 + c)*256 + ky)*256;
#pragma unroll
    for (int n1 = 0; n1 < 16; ++n1) u[n1] = row[n1*16 + lane];
  }

  for (int ii = 0; ii < iters; ++ii) {
    int lt = tp + 4*ii;
    bool act = lt < chunkT;
    int lts = act ? lt : 0;
    // mask loads issued first; consumed only after the fft
    const unsigned int* mp = maskTh
        + (((((size_t)lts*256 + ky)*16 + c) << 8) >> 1) + lane*8;
    unsigned int mu[8];
#pragma unroll
    for (int q = 0; q < 8; ++q) mu[q] = mp[q];
    c32 v[16];
#pragma unroll
    for (int n1 = 0; n1 < 16; ++n1) v[n1] = up2(u[n1]);
    int ltn = tp + 4*(ii+1);
    if (ltn < chunkT) {            // prefetch next Y1 row
      const unsigned int* row = Y1h + ((size_t)(ltn*16 + c)*256 + ky)*256;
#pragma unroll
      for (int n1 = 0; n1 < 16; ++n1) u[n1] = row[n1*16 + lane];
    }
    fft256(v, twh, lds, g, lane);
    if (act) {
#pragma unroll
      for (int p = 0; p < 16; ++p) {
        int j = revmap(p);         // pos = lane*16 + j holds kx = lane + 16*j
        unsigned int um = mu[j >> 1];
        unsigned short us = (j & 1) ? (unsigned short)(um >> 16)
                                    : (unsigned short)(um & 0xffffu);
        float m = h2f(us) * wsc;
        acc[p].x += v[p].x * m;
        acc[p].y += v[p].y * m;
      }
    }
  }
  __syncthreads();
#pragma unroll
  for (int p = 0; p < 16; ++p) lds[g*256 + p*16 + lane] = acc[p];
  __syncthreads();
  // thread tid = kx; gather 4 tp partials x 4 coils, write float4 per plane
  int kx = tid;
  int lane2 = kx & 15, pp = revmap(kx >> 4);
  float vre[4], vim[4];
#pragma unroll
  for (int c2 = 0; c2 < 4; ++c2) {
    float sx = 0.f, sy = 0.f;
#pragma unroll
    for (int t2 = 0; t2 < 4; ++t2) {
      c32 a = lds[(t2*4 + c2)*256 + pp*16 + lane2];
      sx += a.x; sy += a.y;
    }
    vre[c2] = sx; vim[c2] = sy;
  }
  size_t o = (((size_t)kx << 8) + ky)*16 + cq*4;
  float4* pre = (float4*)(out + o);
  float4* pim = (float4*)(out + (size_t)NPIX*NCD + o);
  float4 R = {vre[0], vre[1], vre[2], vre[3]};
  float4 I = {vim[0], vim[1], vim[2], vim[3]};
  if (accum) {
    float4 r0 = *pre, i0 = *pim;
    R.x += r0.x; R.y += r0.y; R.z += r0.z; R.w += r0.w;
    I.x += i0.x; I.y += i0.y; I.z += i0.z; I.w += i0.w;
  }
  *pre = R; *pim = I;
}

extern "C" void kernel_launch(void* const* d_in, const int* in_sizes, int n_in,
                              void* d_out, int out_size, void* d_ws, size_t ws_size,
                              hipStream_t stream) {
  const float* ire  = (const float*)d_in[0];
  const float* iim  = (const float*)d_in[1];
  const float* mask = (const float*)d_in[2];
  const float* sre  = (const float*)d_in[3];
  const float* sim  = (const float*)d_in[4];
  const float* flow = (const float*)d_in[5];
  float* out = (float*)d_out;

  char* ws = (char*)d_ws;
  const size_t smapsT_b = (size_t)NCD * NPIX * 4;             // 4 MB packed
  const size_t w_b      = (size_t)NTD * NPIX * 4;             // 6.3 MB packed
  unsigned int* smapsTh = (unsigned int*)ws;
  unsigned int* whbuf   = (unsigned int*)(ws + smapsT_b);
  size_t base = smapsT_b + w_b;
  size_t rem  = (ws_size > base) ? ws_size - base : 0;

  const size_t maskT_per_t = (size_t)NPIX * NCD * 2;          // 2 MB (fp16)
  const size_t y1_per_t    = (size_t)NCD * NPIX * 4;          // 4 MB (half2)
  int chunk = 1;
  const int cands[8] = {24, 12, 8, 6, 4, 3, 2, 1};
  for (int i = 0; i < 8; ++i) {
    if ((size_t)cands[i] * (maskT_per_t + y1_per_t) <= rem) { chunk = cands[i]; break; }
  }
  unsigned int* maskTh = (unsigned int*)(ws + base);
  unsigned int* Y1h    = (unsigned int*)(ws + base + (size_t)chunk * maskT_per_t);

  kS<<<256, 256, 0, stream>>>(sre, sim, smapsTh);
  kW<<<256, 256, 0, stream>>>(ire, iim, flow, whbuf);
  for (int t0 = 0; t0 < NTD; t0 += chunk) {
    kM<<<dim3(256, 8), 256, 0, stream>>>(mask, maskTh, t0, chunk);
    kA<<<dim3(16, chunk, 4), 256, 0, stream>>>(whbuf, smapsTh, Y1h, t0);
    kB<<<dim3(4, 256), 256, 0, stream>>>(Y1h, maskTh, out, chunk, t0 > 0 ? 1 : 0);
  }
}

// Round 6
// 279.742 us; speedup vs baseline: 1.7854x; 1.0243x over previous
//
#include <hip/hip_runtime.h>
#include <math.h>

#define NCD 16
#define NTD 24
#define NPIX 65536

struct c32 { float x, y; };

__device__ __forceinline__ c32 cadd(c32 a, c32 b){ return {a.x+b.x, a.y+b.y}; }
__device__ __forceinline__ c32 csub(c32 a, c32 b){ return {a.x-b.x, a.y-b.y}; }
__device__ __forceinline__ c32 cmul(c32 a, c32 b){ return {a.x*b.x - a.y*b.y, a.x*b.y + a.y*b.x}; }
__device__ __forceinline__ c32 cnegi(c32 a){ return {a.y, -a.x}; }   // -i*a

__device__ __forceinline__ unsigned short f2h(float f) {
  return __builtin_bit_cast(unsigned short, (_Float16)f);
}
__device__ __forceinline__ float h2f(unsigned short s) {
  return (float)__builtin_bit_cast(_Float16, s);
}
__device__ __forceinline__ unsigned int pk2(c32 v) {
  return (unsigned int)f2h(v.x) | ((unsigned int)f2h(v.y) << 16);
}
__device__ __forceinline__ c32 up2(unsigned int u) {
  c32 r; r.x = h2f((unsigned short)(u & 0xffffu)); r.y = h2f((unsigned short)(u >> 16));
  return r;
}

__constant__ float W16R_[16] = {
  1.0f, 0.9238795325f, 0.7071067812f, 0.3826834324f,
  0.0f,-0.3826834324f,-0.7071067812f,-0.9238795325f,
 -1.0f,-0.9238795325f,-0.7071067812f,-0.3826834324f,
  0.0f, 0.3826834324f, 0.7071067812f, 0.9238795325f };
__constant__ float W16I_[16] = {
  0.0f,-0.3826834324f,-0.7071067812f,-0.9238795325f,
 -1.0f,-0.9238795325f,-0.7071067812f,-0.3826834324f,
  0.0f, 0.3826834324f, 0.7071067812f, 0.9238795325f,
  1.0f, 0.9238795325f, 0.7071067812f, 0.3826834324f };

__device__ __forceinline__ int revmap(int p) { return ((p & 3) << 2) | (p >> 2); }

// 16-pt DFT in registers. Output X[k] at v[revmap(k)].
__device__ __forceinline__ void dft16(c32 v[16]) {
  c32 y[16];
#pragma unroll
  for (int j = 0; j < 4; ++j) {
    c32 a = v[j], b = v[j+4], c = v[j+8], d = v[j+12];
    c32 t0 = cadd(a,c), t1 = csub(a,c), t2 = cadd(b,d), t3 = cnegi(csub(b,d));
    y[j] = cadd(t0,t2);
    if (j == 0) {
      y[4]  = cadd(t1,t3);
      y[8]  = csub(t0,t2);
      y[12] = csub(t1,t3);
    } else {
      c32 w1 = {W16R_[j],        W16I_[j]};
      c32 w2 = {W16R_[(2*j)&15], W16I_[(2*j)&15]};
      c32 w3 = {W16R_[(3*j)&15], W16I_[(3*j)&15]};
      y[4+j]  = cmul(cadd(t1,t3), w1);
      y[8+j]  = cmul(csub(t0,t2), w2);
      y[12+j] = cmul(csub(t1,t3), w3);
    }
  }
#pragma unroll
  for (int q = 0; q < 4; ++q) {
    c32 a = y[4*q], b = y[4*q+1], c = y[4*q+2], d = y[4*q+3];
    c32 t0 = cadd(a,c), t1 = csub(a,c), t2 = cadd(b,d), t3 = cnegi(csub(b,d));
    v[4*q+0] = cadd(t0,t2);
    v[4*q+1] = cadd(t1,t3);
    v[4*q+2] = csub(t0,t2);
    v[4*q+3] = csub(t1,t3);
  }
}

// 256-pt FFT, fp32 mid-exchange (c32 lds[0..4096)). Twiddles packed half2.
__device__ __forceinline__ void fft256(c32 v[16], const unsigned int twh[16],
                                       c32* lds, int g, int lane) {
  dft16(v);
#pragma unroll
  for (int p = 0; p < 16; ++p) v[p] = cmul(v[p], up2(twh[p]));
  __syncthreads();
#pragma unroll
  for (int p = 0; p < 16; ++p) {
    int k1 = revmap(p);
    lds[g*256 + k1*16 + (lane ^ k1)] = v[p];
  }
  __syncthreads();
#pragma unroll
  for (int j = 0; j < 16; ++j)
    v[j] = lds[g*256 + lane*16 + (j ^ lane)];
  dft16(v);
}

// 256-pt FFT, fp16-packed mid-exchange (uint ldsu[0..4352), stride-17 pad).
__device__ __forceinline__ void fft256h(c32 v[16], const unsigned int twh[16],
                                        unsigned int* ldsu, int g, int lane) {
  dft16(v);
#pragma unroll
  for (int p = 0; p < 16; ++p) v[p] = cmul(v[p], up2(twh[p]));
  __syncthreads();
#pragma unroll
  for (int p = 0; p < 16; ++p) {
    int k1 = revmap(p);
    ldsu[g*272 + k1*17 + lane] = pk2(v[p]);   // pad 17: 2-way banks (free)
  }
  __syncthreads();
#pragma unroll
  for (int j = 0; j < 16; ++j)
    v[j] = up2(ldsu[g*272 + lane*17 + j]);
  dft16(v);
}

__device__ __forceinline__ void warp_one(const float* __restrict__ ire,
                                         const float* __restrict__ iim,
                                         int nx, int ny, float fx, float fy,
                                         float s, c32* v) {
  float xf = fminf(fmaxf((float)nx + fx, 0.0f), 255.0f);
  float yf = fminf(fmaxf((float)ny + fy, 0.0f), 255.0f);
  float x0f = fminf(floorf(xf), 254.0f);
  float y0f = fminf(floorf(yf), 254.0f);
  int i00 = (int)x0f * 256 + (int)y0f;
  float wx = xf - x0f, wy = yf - y0f;
  float w00 = (1.f-wx)*(1.f-wy), w01 = (1.f-wx)*wy;
  float w10 = wx*(1.f-wy),       w11 = wx*wy;
  float re = w00*ire[i00] + w01*ire[i00+1] + w10*ire[i00+256] + w11*ire[i00+257];
  float im = w00*iim[i00] + w01*iim[i00+1] + w10*iim[i00+256] + w11*iim[i00+257];
  v->x = re*s; v->y = im*s;
}

// --- kP: merged prep (chunk==24 fast path) ---------------------------------
// bx 0..2047   : mask transpose (ky = bx>>3, c-pair = bx&7), float4 loads
// bx 2048..2303: smaps transpose -> packed half2 [c][nx][ny]
// bx 2304..2559: warp + (-1)^{nx+ny} -> packed half2 [t][nx][ny]
__global__ __launch_bounds__(256) void kP(const float* __restrict__ sre,
                                          const float* __restrict__ sim,
                                          const float* __restrict__ ire,
                                          const float* __restrict__ iim,
                                          const float* __restrict__ flow,
                                          const float* __restrict__ mask,
                                          unsigned int* __restrict__ smapsTh,
                                          unsigned int* __restrict__ wh,
                                          unsigned int* __restrict__ maskTh) {
  __shared__ float shf[6400];          // 25.6 KB, role-dependent
  int bx = blockIdx.x, tid = threadIdx.x;
  if (bx < 2048) {
    // ---- mask role: [kx][ky][c][t] -> [t][ky][c][pos], pos=nibbleswap(kx)
    unsigned short* lm = (unsigned short*)shf;   // [256][49] fp16
    int ky = bx >> 3, c0 = (bx & 7) * 2;
    const float4* m4 = (const float4*)mask;
    size_t rowbase = ((size_t)ky*384 + (size_t)c0*24) >> 2;  // float4 units
#pragma unroll
    for (int i = 0; i < 12; ++i) {
      int idx = tid + 256*i;           // 3072 float4s = 256 kx * 12
      int kx = idx / 12, r = idx - kx*12;
      float4 v = m4[(size_t)kx*24576 + rowbase + r];
      int b = kx*49 + r*4;             // ctl = r*4..r*4+3
      lm[b+0] = f2h(v.x); lm[b+1] = f2h(v.y);
      lm[b+2] = f2h(v.z); lm[b+3] = f2h(v.w);
    }
    __syncthreads();
#pragma unroll
    for (int i = 0; i < 24; ++i) {
      int e = tid + 256*i;             // 6144 = 48 ctl * 128 uint-pos
      int ctl = e >> 7;
      int posh = (e & 127) * 2;
      int hi = (ctl >= 24) ? 1 : 0;
      int cc = c0 + hi;
      int ltt = ctl - hi*24;
      int kxa = ((posh & 15) << 4) | (posh >> 4);
      int kxb = kxa + 16;              // nibbleswap(posh+1), posh even
      unsigned int a = lm[kxa*49 + ctl], b = lm[kxb*49 + ctl];
      size_t base = (((((size_t)ltt*256 + ky)*16 + cc) << 8) + posh) >> 1;
      maskTh[base] = a | (b << 16);
    }
  } else if (bx < 2304) {
    // ---- smaps role
    int nx = bx - 2048;
    float rre[16];
#pragma unroll
    for (int it = 0; it < 16; ++it) {
      int e = it*256 + tid;            // e = ny*16 + c
      shf[(e & 15)*260 + (e >> 4)] = sre[(size_t)nx*4096 + e];
    }
    __syncthreads();
#pragma unroll
    for (int c = 0; c < 16; ++c) rre[c] = shf[c*260 + tid];
    __syncthreads();
#pragma unroll
    for (int it = 0; it < 16; ++it) {
      int e = it*256 + tid;
      shf[(e & 15)*260 + (e >> 4)] = sim[(size_t)nx*4096 + e];
    }
    __syncthreads();
#pragma unroll
    for (int c = 0; c < 16; ++c) {
      c32 v = { rre[c], shf[c*260 + tid] };
      smapsTh[(size_t)c*NPIX + nx*256 + tid] = pk2(v);
    }
  } else {
    // ---- warp role, two t-halves (LDS [256][25])
    int nx = bx - 2304;
    int ny = tid;
    float s = ((nx + ny) & 1) ? -1.0f : 1.0f;
    const float4* f4 = (const float4*)(flow + (size_t)nx*12288);
    for (int h = 0; h < 2; ++h) {
      if (h) __syncthreads();
#pragma unroll
      for (int i = 0; i < 6; ++i) {
        int idx = tid + 256*i;         // 1536 float4 = 256 ny * 6
        int yy = idx / 6, q = idx - yy*6;
        int d = q / 3, r = q - d*3;
        float4 v = f4[(yy*48 + d*24 + h*12) / 4 + r];
        int b = yy*25 + d*12 + r*4;
        shf[b+0] = v.x; shf[b+1] = v.y; shf[b+2] = v.z; shf[b+3] = v.w;
      }
      __syncthreads();
      for (int tl = 0; tl < 12; ++tl) {
        int t = h*12 + tl;
        float fx = shf[ny*25 + tl];
        float fy = shf[ny*25 + 12 + tl];
        c32 v;
        warp_one(ire, iim, nx, ny, fx, fy, s, &v);
        wh[(size_t)t*NPIX + nx*256 + ny] = pk2(v);
      }
    }
  }
}

// --- fallback-path kernels (chunk < 24) ------------------------------------
__global__ __launch_bounds__(256) void kS(const float* __restrict__ sre,
                                          const float* __restrict__ sim,
                                          unsigned int* __restrict__ smapsTh) {
  __shared__ float lre[16*260];
  __shared__ float lim[16*260];
  int nx = blockIdx.x, tid = threadIdx.x;
#pragma unroll
  for (int it = 0; it < 16; ++it) {
    int e = it*256 + tid;
    lre[(e & 15)*260 + (e >> 4)] = sre[(size_t)nx*4096 + e];
    lim[(e & 15)*260 + (e >> 4)] = sim[(size_t)nx*4096 + e];
  }
  __syncthreads();
#pragma unroll
  for (int c = 0; c < 16; ++c) {
    c32 v = { lre[c*260 + tid], lim[c*260 + tid] };
    smapsTh[(size_t)c*NPIX + nx*256 + tid] = pk2(v);
  }
}

__global__ __launch_bounds__(256) void kW(const float* __restrict__ ire,
                                          const float* __restrict__ iim,
                                          const float* __restrict__ flow,
                                          unsigned int* __restrict__ wh) {
  __shared__ float fl[256*49];
  int nx = blockIdx.x, tid = threadIdx.x;
  const float* src = flow + (size_t)nx*12288;
#pragma unroll
  for (int it = 0; it < 48; ++it) {
    int e = it*256 + tid;
    fl[(e/48)*49 + (e%48)] = src[e];
  }
  __syncthreads();
  int ny = tid;
  float s = ((nx + ny) & 1) ? -1.0f : 1.0f;
  for (int t = 0; t < NTD; ++t) {
    c32 v;
    warp_one(ire, iim, nx, ny, fl[ny*49 + t], fl[ny*49 + 24 + t], s, &v);
    wh[(size_t)t*NPIX + nx*256 + ny] = pk2(v);
  }
}

__global__ __launch_bounds__(256) void kM(const float* __restrict__ mask,
                                          unsigned int* __restrict__ maskTh,
                                          int t0, int chunkT) {
  __shared__ unsigned short lm[256*49];
  int ky = blockIdx.x, c0 = blockIdx.y*2, tid = threadIdx.x;
  int nct = 2*chunkT;
  int total = 256*nct;
  for (int e = tid; e < total; e += 256) {
    int kx = e / nct, ctl = e - kx*nct;
    int hi = (ctl >= chunkT) ? 1 : 0;
    int cc = c0 + hi;
    int tt = t0 + ctl - hi*chunkT;
    lm[kx*49 + ctl] = f2h(mask[(size_t)kx*98304 + ky*384 + cc*24 + tt]);
  }
  __syncthreads();
  int wtotal = nct*128;
  for (int e = tid; e < wtotal; e += 256) {
    int ctl = e >> 7;
    int posh = (e & 127) * 2;
    int hi = (ctl >= chunkT) ? 1 : 0;
    int cc = c0 + hi;
    int ltt = ctl - hi*chunkT;
    int kxa = ((posh & 15) << 4) | (posh >> 4);
    int kxb = kxa + 16;
    unsigned int a = lm[kxa*49 + ctl], b = lm[kxb*49 + ctl];
    size_t base = (((((size_t)ltt*256 + ky)*16 + cc) << 8) + posh) >> 1;
    maskTh[base] = a | (b << 16);
  }
}

// --- kA: row FFTs along ny -> Y1h[lt][c][ky][nx] packed half2 ---
__global__ __launch_bounds__(256) void kA(const unsigned int* __restrict__ wh,
                                          const unsigned int* __restrict__ smapsTh,
                                          unsigned int* __restrict__ Y1h, int t0) {
  __shared__ unsigned int fftws[4352];   // 17 KB fp16 fft mid-exchange
  __shared__ unsigned int stage[4096];   // 16 KB output staging (disjoint!)
  int tid = threadIdx.x, g = tid >> 4, lane = tid & 15;
  int lt = blockIdx.y, t = t0 + lt;
  int nx0 = blockIdx.x*16, nx = nx0 + g;
  int c0 = blockIdx.z*4;

  unsigned int wr[16];
  const unsigned int* wrow = wh + (size_t)t*NPIX + nx*256;
#pragma unroll
  for (int n1 = 0; n1 < 16; ++n1) wr[n1] = wrow[n1*16 + lane];

  unsigned int twh[16];
#pragma unroll
  for (int p = 0; p < 16; ++p) {
    int k1 = revmap(p);
    float ang = -6.283185307179586f * (float)(lane * k1) * (1.0f/256.0f);
    float sv, cv; __sincosf(ang, &sv, &cv);
    c32 tw; tw.x = cv; tw.y = sv;
    twh[p] = pk2(tw);
  }

  unsigned int su[16];
  {
    const unsigned int* srow = smapsTh + (size_t)c0*NPIX + nx*256;
#pragma unroll
    for (int n1 = 0; n1 < 16; ++n1) su[n1] = srow[n1*16 + lane];
  }

  for (int ci = 0; ci < 4; ++ci) {
    int c = c0 + ci;
    c32 v[16];
#pragma unroll
    for (int n1 = 0; n1 < 16; ++n1) v[n1] = cmul(up2(wr[n1]), up2(su[n1]));
    if (ci < 3) {
      const unsigned int* srow = smapsTh + (size_t)(c + 1)*NPIX + nx*256;
#pragma unroll
      for (int n1 = 0; n1 < 16; ++n1) su[n1] = srow[n1*16 + lane];
    }
    fft256h(v, twh, fftws, g, lane);
#pragma unroll
    for (int p = 0; p < 16; ++p) {
      int ky = lane + 16*revmap(p);
      stage[ky*16 + (g ^ lane)] = pk2(v[p]);
    }
    __syncthreads();
    unsigned int* dst = Y1h + (((size_t)lt*16 + c) << 16) + nx0;
#pragma unroll
    for (int it = 0; it < 16; ++it) {
      int e = it*256 + tid;
      int ky = e >> 4, j = e & 15;
      dst[(size_t)ky*256 + j] = stage[ky*16 + (j ^ (ky & 15))];
    }
  }
}

// --- kB: column FFTs + mask-weighted t-reduction -> out, no atomics ---
__global__ __launch_bounds__(256) void kB(const unsigned int* __restrict__ Y1h,
                                          const unsigned int* __restrict__ maskTh,
                                          float* __restrict__ out,
                                          int chunkT, int accum) {
  __shared__ c32 lds[4096];
  int tid = threadIdx.x, g = tid >> 4, lane = tid & 15;
  int ci = g & 3, tp = g >> 2;
  int cq = blockIdx.x, ky = blockIdx.y;
  int c = cq*4 + ci;

  unsigned int twh[16];
#pragma unroll
  for (int p = 0; p < 16; ++p) {
    int k1 = revmap(p);
    float ang = -6.283185307179586f * (float)(lane * k1) * (1.0f/256.0f);
    float sv, cv; __sincosf(ang, &sv, &cv);
    c32 tw; tw.x = cv; tw.y = sv;
    twh[p] = pk2(tw);
  }

  c32 acc[16];
#pragma unroll
  for (int p = 0; p < 16; ++p) { acc[p].x = 0.f; acc[p].y = 0.f; }
  float wsc = (((lane + ky) & 1) ? -1.0f : 1.0f) * (1.0f/256.0f);

  int iters = (chunkT + 3) >> 2;
  unsigned int u[16];
#pragma unroll
  for (int n1 = 0; n1 < 16; ++n1) u[n1] = 0;
  if (tp < chunkT) {
    const unsigned int* row = Y1h + ((size_t)(tp*16 + c)*256 + ky)*256;
#pragma unroll
    for (int n1 = 0; n1 < 16; ++n1) u[n1] = row[n1*16 + lane];
  }

  for (int ii = 0; ii < iters; ++ii) {
    int lt = tp + 4*ii;
    bool act = lt < chunkT;
    int lts = act ? lt : 0;
    const unsigned int* mp = maskTh
        + (((((size_t)lts*256 + ky)*16 + c) << 8) >> 1) + lane*8;
    unsigned int mu[8];
#pragma unroll
    for (int q = 0; q < 8; ++q) mu[q] = mp[q];
    c32 v[16];
#pragma unroll
    for (int n1 = 0; n1 < 16; ++n1) v[n1] = up2(u[n1]);
    int ltn = tp + 4*(ii+1);
    if (ltn < chunkT) {
      const unsigned int* row = Y1h + ((size_t)(ltn*16 + c)*256 + ky)*256;
#pragma unroll
      for (int n1 = 0; n1 < 16; ++n1) u[n1] = row[n1*16 + lane];
    }
    fft256(v, twh, lds, g, lane);
    if (act) {
#pragma unroll
      for (int p = 0; p < 16; ++p) {
        int j = revmap(p);
        unsigned int um = mu[j >> 1];
        unsigned short us = (j & 1) ? (unsigned short)(um >> 16)
                                    : (unsigned short)(um & 0xffffu);
        float m = h2f(us) * wsc;
        acc[p].x += v[p].x * m;
        acc[p].y += v[p].y * m;
      }
    }
  }
  __syncthreads();
#pragma unroll
  for (int p = 0; p < 16; ++p) lds[g*256 + p*16 + lane] = acc[p];
  __syncthreads();
  int kx = tid;
  int lane2 = kx & 15, pp = revmap(kx >> 4);
  float vre[4], vim[4];
#pragma unroll
  for (int c2 = 0; c2 < 4; ++c2) {
    float sx = 0.f, sy = 0.f;
#pragma unroll
    for (int t2 = 0; t2 < 4; ++t2) {
      c32 a = lds[(t2*4 + c2)*256 + pp*16 + lane2];
      sx += a.x; sy += a.y;
    }
    vre[c2] = sx; vim[c2] = sy;
  }
  size_t o = (((size_t)kx << 8) + ky)*16 + cq*4;
  float4* pre = (float4*)(out + o);
  float4* pim = (float4*)(out + (size_t)NPIX*NCD + o);
  float4 R = {vre[0], vre[1], vre[2], vre[3]};
  float4 I = {vim[0], vim[1], vim[2], vim[3]};
  if (accum) {
    float4 r0 = *pre, i0 = *pim;
    R.x += r0.x; R.y += r0.y; R.z += r0.z; R.w += r0.w;
    I.x += i0.x; I.y += i0.y; I.z += i0.z; I.w += i0.w;
  }
  *pre = R; *pim = I;
}

extern "C" void kernel_launch(void* const* d_in, const int* in_sizes, int n_in,
                              void* d_out, int out_size, void* d_ws, size_t ws_size,
                              hipStream_t stream) {
  const float* ire  = (const float*)d_in[0];
  const float* iim  = (const float*)d_in[1];
  const float* mask = (const float*)d_in[2];
  const float* sre  = (const float*)d_in[3];
  const float* sim  = (const float*)d_in[4];
  const float* flow = (const float*)d_in[5];
  float* out = (float*)d_out;

  char* ws = (char*)d_ws;
  const size_t smapsT_b = (size_t)NCD * NPIX * 4;             // 4 MB packed
  const size_t w_b      = (size_t)NTD * NPIX * 4;             // 6.3 MB packed
  unsigned int* smapsTh = (unsigned int*)ws;
  unsigned int* whbuf   = (unsigned int*)(ws + smapsT_b);
  size_t base = smapsT_b + w_b;
  size_t rem  = (ws_size > base) ? ws_size - base : 0;

  const size_t maskT_per_t = (size_t)NPIX * NCD * 2;          // 2 MB (fp16)
  const size_t y1_per_t    = (size_t)NCD * NPIX * 4;          // 4 MB (half2)
  int chunk = 1;
  const int cands[8] = {24, 12, 8, 6, 4, 3, 2, 1};
  for (int i = 0; i < 8; ++i) {
    if ((size_t)cands[i] * (maskT_per_t + y1_per_t) <= rem) { chunk = cands[i]; break; }
  }
  unsigned int* maskTh = (unsigned int*)(ws + base);
  unsigned int* Y1h    = (unsigned int*)(ws + base + (size_t)chunk * maskT_per_t);

  if (chunk == 24) {
    kP<<<2560, 256, 0, stream>>>(sre, sim, ire, iim, flow, mask,
                                 smapsTh, whbuf, maskTh);
    kA<<<dim3(16, 24, 4), 256, 0, stream>>>(whbuf, smapsTh, Y1h, 0);
    kB<<<dim3(4, 256), 256, 0, stream>>>(Y1h, maskTh, out, 24, 0);
  } else {
    kS<<<256, 256, 0, stream>>>(sre, sim, smapsTh);
    kW<<<256, 256, 0, stream>>>(ire, iim, flow, whbuf);
    for (int t0 = 0; t0 < NTD; t0 += chunk) {
      kM<<<dim3(256, 8), 256, 0, stream>>>(mask, maskTh, t0, chunk);
      kA<<<dim3(16, chunk, 4), 256, 0, stream>>>(whbuf, smapsTh, Y1h, t0);
      kB<<<dim3(4, 256), 256, 0, stream>>>(Y1h, maskTh, out, chunk, t0 > 0 ? 1 : 0);
    }
  }
}